// Round 4
// baseline (3041.358 us; speedup 1.0000x reference)
//
#include <hip/hip_runtime.h>
#include <initializer_list>
#include <cstdint>
#include <cstddef>

// CommCellInnerRNN on MI355X.
// Decomposition:
//   phase1: h1p = LSTM(inputs, rnn_h1, rnn_c1; Wx1,Wh1,b1)
//           feat = LSTM(h1p, rnn_h2, rnn_c2; Wx2,Wh2,b2)
//           F1   = feat @ CWx1[261:773] + Cb1          (features are constant over t)
//   loop t=0..16:
//           xvar_t = [gather(signals,pres_t) | onehot(dir) | dist | 0pad]  (261->288)
//           z1 = F1 + xvar_t @ CWx1[0:261] + h1 @ CWh1
//           nh1,nc1 = gates(z1, c1); carry-update masked
//           z2 = nh1 @ CWx2 + h2 @ CWh2 + Cb2
//           nh2,nc2 = gates(z2, c2); carry-update masked
//   out = [h2_final, h2_final, feat]   (out_signals == final h2 carry: t=16 mask==1)
// Precision: split-bf16 (hi+lo planes, 3 MFMA terms: hh + lh + hl) == ~fp32 accuracy.

typedef short short8 __attribute__((ext_vector_type(8)));
typedef float f32x4 __attribute__((ext_vector_type(4)));
typedef unsigned short us;

#define N_AG 4096

// ---------- numeric helpers ----------
__device__ __forceinline__ us f2bf(float x) {
  unsigned int u = __float_as_uint(x);
  unsigned int r = (u + 0x7fffu + ((u >> 16) & 1u)) >> 16;  // RNE
  return (us)r;
}
__device__ __forceinline__ float bf2f(us b) {
  return __uint_as_float(((unsigned int)b) << 16);
}
__device__ __forceinline__ void split_bf(float v, us& hi, us& lo) {
  us h = f2bf(v);
  hi = h;
  lo = f2bf(v - bf2f(h));  // v - hi exact in fp32
}
__device__ __forceinline__ float sigm(float x) { return 1.f / (1.f + __expf(-x)); }
__device__ __forceinline__ float tanh_f(float x) {
  float e = __expf(2.f * x);
  return 1.f - 2.f / (1.f + e);
}

// ---------- GEMM: C[M=4096 x N] = base + sum_p A_p(MxK_p) * B_p^T(NxK_p) ----------
// A,B are bf16 planes (row-major, ld = K). 128x128 tile, 4 waves, 16x16x32 MFMA,
// global_load_lds(16B) staging with XOR k-slot swizzle (<=2-way LDS bank aliasing).
struct Pair { const us* A; const us* B; int K; };
struct GemmArgs { Pair pr[6]; int np; int N; const float* base; int mode; float* C; };

typedef __attribute__((address_space(1))) const unsigned int as1u;
typedef __attribute__((address_space(3))) unsigned int as3u;
__device__ __forceinline__ void gload16(const void* g, void* l) {
  __builtin_amdgcn_global_load_lds((as1u*)g, (as3u*)l, 16, 0, 0);
}

__global__ __launch_bounds__(256) void k_gemm(GemmArgs g) {
  __shared__ __align__(16) us lA[128 * 32];
  __shared__ __align__(16) us lB[128 * 32];
  const int t = threadIdx.x;
  const int w = t >> 6, l = t & 63;
  const int bm = blockIdx.y, bn = blockIdx.x;
  const int wm = w & 1, wn = w >> 1;
  const int fr = l & 15, ks = l >> 4;
  const int srow = t >> 2;                          // staging row (0..63; +64 round 1)
  const int sslot = (t & 3) ^ ((srow >> 1) & 3);    // swizzled source k-slot
  f32x4 acc[4][4] = {};

  for (int p = 0; p < g.np; ++p) {
    const us* A = g.pr[p].A;
    const us* B = g.pr[p].B;
    const int K = g.pr[p].K;
    const us* Ab = A + (size_t)bm * 128 * K;
    const us* Bb = B + (size_t)bn * 128 * K;
    for (int k0 = 0; k0 < K; k0 += 32) {
      __syncthreads();
#pragma unroll
      for (int r = 0; r < 2; ++r) {
        const int row = srow + r * 64;
        gload16(Ab + (size_t)row * K + k0 + sslot * 8, (char*)lA + r * 4096 + w * 1024);
        gload16(Bb + (size_t)row * K + k0 + sslot * 8, (char*)lB + r * 4096 + w * 1024);
      }
      __syncthreads();
      short8 af[4], bfr[4];
#pragma unroll
      for (int mi = 0; mi < 4; ++mi) {
        const int row = wm * 64 + mi * 16 + fr;
        af[mi] = *(const short8*)((const char*)lA + row * 64 + ((ks ^ ((row >> 1) & 3)) * 16));
      }
#pragma unroll
      for (int ni = 0; ni < 4; ++ni) {
        const int row = wn * 64 + ni * 16 + fr;
        bfr[ni] = *(const short8*)((const char*)lB + row * 64 + ((ks ^ ((row >> 1) & 3)) * 16));
      }
#pragma unroll
      for (int mi = 0; mi < 4; ++mi)
#pragma unroll
        for (int ni = 0; ni < 4; ++ni)
          acc[mi][ni] = __builtin_amdgcn_mfma_f32_16x16x32_bf16(af[mi], bfr[ni], acc[mi][ni], 0, 0, 0);
    }
  }
  const int N = g.N;
#pragma unroll
  for (int mi = 0; mi < 4; ++mi) {
#pragma unroll
    for (int ni = 0; ni < 4; ++ni) {
#pragma unroll
      for (int rr = 0; rr < 4; ++rr) {
        const int grow = bm * 128 + wm * 64 + mi * 16 + ks * 4 + rr;
        const int gcol = bn * 128 + wn * 64 + ni * 16 + fr;
        float v = acc[mi][ni][rr];
        if (g.mode == 1) v += g.base[gcol];
        else if (g.mode == 2) v += g.base[(size_t)grow * N + gcol];
        g.C[(size_t)grow * N + gcol] = v;
      }
    }
  }
}

// ---------- weight transpose + split: src (Krows x Nout) -> planes (Nout x Kpad) ----------
__global__ __launch_bounds__(256) void k_transpose_split(const float* __restrict__ src,
    int Nout, int Kreal, int Kpad, int roff, us* __restrict__ hi, us* __restrict__ lo) {
  int idx = blockIdx.x * 256 + threadIdx.x;
  if (idx >= Nout * Kpad) return;
  int no = idx % Nout;     // consecutive threads -> coalesced src read
  int k = idx / Nout;
  float v = (k < Kreal) ? src[(size_t)(roff + k) * Nout + no] : 0.f;
  us h, l_;
  split_bf(v, h, l_);
  hi[(size_t)no * Kpad + k] = h;
  lo[(size_t)no * Kpad + k] = l_;
}

// ---------- fp32 -> (optional fp32 copy) + bf16 hi/lo planes ----------
__global__ __launch_bounds__(256) void k_split(const float* __restrict__ src, int n,
    float* __restrict__ f, us* __restrict__ hi, us* __restrict__ lo) {
  int idx = blockIdx.x * 256 + threadIdx.x;
  if (idx >= n) return;
  float v = src[idx];
  if (f) f[idx] = v;
  if (hi) { us h, l_; split_bf(v, h, l_); hi[idx] = h; lo[idx] = l_; }
}

// ---------- per-step varying input: [gather(256) | onehot(4) | dist(1) | 0pad(27)] ----------
__global__ __launch_bounds__(256) void k_xvar(const int* __restrict__ pi,
    const float* __restrict__ sig, int t, us* __restrict__ xh, us* __restrict__ xl) {
  int idx = blockIdx.x * 256 + threadIdx.x;
  if (idx >= N_AG * 288) return;
  int n = idx / 288, c = idx - n * 288;
  float v = 0.f;
  if (t < 16) {
    int p = pi[n * 48 + 3 * t];
    if (c < 256) v = (p >= 0) ? sig[(size_t)p * 256 + c] : 0.f;
    else if (c < 260) v = ((c - 256) == pi[n * 48 + 3 * t + 2]) ? 1.f : 0.f;
    else if (c == 260) v = (float)pi[n * 48 + 3 * t + 1];
  } else {
    if (c < 256) v = sig[(size_t)n * 256 + c];  // self row; onehot/dist padded 0
  }
  us h, l_;
  split_bf(v, h, l_);
  xh[idx] = h;
  xl[idx] = l_;
}

// ---------- LSTM gate kernels ----------
__global__ __launch_bounds__(256) void k_ew_simple(const float* __restrict__ Z,
    const float* __restrict__ cin, float* __restrict__ hf, us* __restrict__ hh, us* __restrict__ hl) {
  int idx = blockIdx.x * 256 + threadIdx.x;
  if (idx >= N_AG * 512) return;
  int n = idx >> 9, u = idx & 511;
  const float* zr = Z + (size_t)n * 2048;
  float nc = sigm(zr[512 + u]) * cin[idx] + sigm(zr[u]) * tanh_f(zr[1024 + u]);
  float nh = sigm(zr[1536 + u]) * tanh_f(nc);
  if (hf) hf[idx] = nh;
  us h, l_;
  split_bf(nh, h, l_);
  hh[idx] = h;
  hl[idx] = l_;
}

__global__ __launch_bounds__(256) void k_ew_comm1(const float* __restrict__ Z,
    const int* __restrict__ pi, int t, float* __restrict__ h, float* __restrict__ c,
    us* __restrict__ hh, us* __restrict__ hl, us* __restrict__ nhh, us* __restrict__ nhl) {
  int idx = blockIdx.x * 256 + threadIdx.x;
  if (idx >= N_AG * 512) return;
  int n = idx >> 9, u = idx & 511;
  const float* zr = Z + (size_t)n * 2048;
  float cold = c[idx];
  float nc = sigm(zr[512 + u]) * cold + sigm(zr[u]) * tanh_f(zr[1024 + u]);
  float nh = sigm(zr[1536 + u]) * tanh_f(nc);
  bool m = (t == 16) ? true : (pi[n * 48 + 3 * t] >= 0);
  float hn = m ? nh : h[idx];
  float cn = m ? nc : cold;
  h[idx] = hn;
  c[idx] = cn;
  us a, b;
  split_bf(hn, a, b); hh[idx] = a; hl[idx] = b;    // masked carry (next-step GEMM)
  split_bf(nh, a, b); nhh[idx] = a; nhl[idx] = b;  // pre-mask nh1 (layer-2 input)
}

__global__ __launch_bounds__(256) void k_ew_comm2(const float* __restrict__ Z,
    const int* __restrict__ pi, int t, float* __restrict__ h, float* __restrict__ c,
    us* __restrict__ hh, us* __restrict__ hl) {
  int idx = blockIdx.x * 256 + threadIdx.x;
  if (idx >= N_AG * 256) return;
  int n = idx >> 8, u = idx & 255;
  const float* zr = Z + (size_t)n * 1024;
  float cold = c[idx];
  float nc = sigm(zr[256 + u]) * cold + sigm(zr[u]) * tanh_f(zr[512 + u]);
  float nh = sigm(zr[768 + u]) * tanh_f(nc);
  bool m = (t == 16) ? true : (pi[n * 48 + 3 * t] >= 0);
  float hn = m ? nh : h[idx];
  float cn = m ? nc : cold;
  h[idx] = hn;
  c[idx] = cn;
  us a, b;
  split_bf(hn, a, b); hh[idx] = a; hl[idx] = b;
}

__global__ __launch_bounds__(256) void k_out(const float* __restrict__ h2,
    const float* __restrict__ feat, float* __restrict__ out) {
  int idx = blockIdx.x * 256 + threadIdx.x;
  if (idx >= N_AG * 1024) return;
  int n = idx >> 10, cc = idx & 1023;
  out[idx] = (cc < 512) ? h2[(size_t)n * 256 + (cc & 255)] : feat[(size_t)n * 512 + cc - 512];
}

// ---------- host ----------
extern "C" void kernel_launch(void* const* d_in, const int* in_sizes, int n_in,
                              void* d_out, int out_size, void* d_ws, size_t ws_size,
                              hipStream_t stream) {
  const float* inputs  = (const float*)d_in[0];
  const int*   pres    = (const int*)d_in[1];
  const float* rnn_h1  = (const float*)d_in[2];
  const float* rnn_c1  = (const float*)d_in[3];
  const float* rnn_h2  = (const float*)d_in[4];
  const float* rnn_c2  = (const float*)d_in[5];
  const float* comm_h1 = (const float*)d_in[6];
  const float* comm_c1 = (const float*)d_in[7];
  const float* comm_h2 = (const float*)d_in[8];
  const float* comm_c2 = (const float*)d_in[9];
  const float* signals = (const float*)d_in[10];
  const float* Wx1 = (const float*)d_in[11];
  const float* Wh1 = (const float*)d_in[12];
  const float* b1  = (const float*)d_in[13];
  const float* Wx2 = (const float*)d_in[14];
  const float* Wh2 = (const float*)d_in[15];
  const float* b2  = (const float*)d_in[16];
  const float* CWx1 = (const float*)d_in[17];
  const float* CWh1 = (const float*)d_in[18];
  const float* Cb1  = (const float*)d_in[19];
  const float* CWx2 = (const float*)d_in[20];
  const float* CWh2 = (const float*)d_in[21];
  const float* Cb2  = (const float*)d_in[22];
  float* out = (float*)d_out;
  (void)in_sizes; (void)n_in; (void)out_size;

  char* wsb = (char*)d_ws;
  size_t off = 0;
  auto alloc = [&](size_t bytes) -> char* {
    char* p = wsb + off;
    off = (off + bytes + 255) & ~(size_t)255;
    return p;
  };
  // transposed split weights (Nout x Kpad planes, bf16)
  us* wx1t_h = (us*)alloc(2048 * 512 * 2); us* wx1t_l = (us*)alloc(2048 * 512 * 2);
  us* wh1t_h = (us*)alloc(2048 * 512 * 2); us* wh1t_l = (us*)alloc(2048 * 512 * 2);
  us* wx2t_h = (us*)alloc(2048 * 512 * 2); us* wx2t_l = (us*)alloc(2048 * 512 * 2);
  us* wh2t_h = (us*)alloc(2048 * 512 * 2); us* wh2t_l = (us*)alloc(2048 * 512 * 2);
  us* cx1vt_h = (us*)alloc(2048 * 288 * 2); us* cx1vt_l = (us*)alloc(2048 * 288 * 2);
  us* cx1ft_h = (us*)alloc(2048 * 512 * 2); us* cx1ft_l = (us*)alloc(2048 * 512 * 2);
  us* ch1t_h = (us*)alloc(2048 * 512 * 2); us* ch1t_l = (us*)alloc(2048 * 512 * 2);
  us* cx2t_h = (us*)alloc(1024 * 512 * 2); us* cx2t_l = (us*)alloc(1024 * 512 * 2);
  us* ch2t_h = (us*)alloc(1024 * 256 * 2); us* ch2t_l = (us*)alloc(1024 * 256 * 2);
  // activation planes
  us* in_h  = (us*)alloc(4096 * 512 * 2); us* in_l  = (us*)alloc(4096 * 512 * 2);
  us* rh1_h = (us*)alloc(4096 * 512 * 2); us* rh1_l = (us*)alloc(4096 * 512 * 2);
  us* rh2_h = (us*)alloc(4096 * 512 * 2); us* rh2_l = (us*)alloc(4096 * 512 * 2);
  us* h1p_h = (us*)alloc(4096 * 512 * 2); us* h1p_l = (us*)alloc(4096 * 512 * 2);
  us* ft_h  = (us*)alloc(4096 * 512 * 2); us* ft_l  = (us*)alloc(4096 * 512 * 2);
  us* h1_h  = (us*)alloc(4096 * 512 * 2); us* h1_l  = (us*)alloc(4096 * 512 * 2);
  us* nh1_h = (us*)alloc(4096 * 512 * 2); us* nh1_l = (us*)alloc(4096 * 512 * 2);
  us* h2_h  = (us*)alloc(4096 * 256 * 2); us* h2_l  = (us*)alloc(4096 * 256 * 2);
  us* xv_h  = (us*)alloc(4096 * 288 * 2); us* xv_l  = (us*)alloc(4096 * 288 * 2);
  // fp32 buffers
  float* feat = (float*)alloc(4096 * 512 * 4);
  float* F1 = (float*)alloc((size_t)4096 * 2048 * 4);
  float* Z1 = (float*)alloc((size_t)4096 * 2048 * 4);
  float* Z2 = (float*)alloc((size_t)4096 * 1024 * 4);
  float* h1 = (float*)alloc(4096 * 512 * 4);
  float* c1 = (float*)alloc(4096 * 512 * 4);
  float* h2 = (float*)alloc(4096 * 256 * 4);
  float* c2 = (float*)alloc(4096 * 256 * 4);
  if (off > ws_size) return;  // workspace too small; cannot run safely

  auto tsp = [&](const float* src, int Nout, int Kreal, int Kpad, int roff, us* hi, us* lo) {
    int tot = Nout * Kpad;
    k_transpose_split<<<dim3((tot + 255) / 256), dim3(256), 0, stream>>>(src, Nout, Kreal, Kpad, roff, hi, lo);
  };
  tsp(Wx1, 2048, 512, 512, 0, wx1t_h, wx1t_l);
  tsp(Wh1, 2048, 512, 512, 0, wh1t_h, wh1t_l);
  tsp(Wx2, 2048, 512, 512, 0, wx2t_h, wx2t_l);
  tsp(Wh2, 2048, 512, 512, 0, wh2t_h, wh2t_l);
  tsp(CWx1, 2048, 261, 288, 0, cx1vt_h, cx1vt_l);      // varying rows 0..260 -> Kpad 288
  tsp(CWx1, 2048, 512, 512, 261, cx1ft_h, cx1ft_l);    // feature rows 261..772
  tsp(CWh1, 2048, 512, 512, 0, ch1t_h, ch1t_l);
  tsp(CWx2, 1024, 512, 512, 0, cx2t_h, cx2t_l);
  tsp(CWh2, 1024, 256, 256, 0, ch2t_h, ch2t_l);

  auto spl = [&](const float* src, int n, float* f, us* hi, us* lo) {
    k_split<<<dim3((n + 255) / 256), dim3(256), 0, stream>>>(src, n, f, hi, lo);
  };
  spl(inputs, 4096 * 512, nullptr, in_h, in_l);
  spl(rnn_h1, 4096 * 512, nullptr, rh1_h, rh1_l);
  spl(rnn_h2, 4096 * 512, nullptr, rh2_h, rh2_l);
  spl(comm_h1, 4096 * 512, h1, h1_h, h1_l);
  spl(comm_c1, 4096 * 512, c1, nullptr, nullptr);
  spl(comm_h2, 4096 * 256, h2, h2_h, h2_l);
  spl(comm_c2, 4096 * 256, c2, nullptr, nullptr);

  auto gemm = [&](std::initializer_list<Pair> ps, int Ncols, const float* base, int mode, float* C) {
    GemmArgs ga{};
    int i = 0;
    for (auto& p : ps) ga.pr[i++] = p;
    ga.np = i; ga.N = Ncols; ga.base = base; ga.mode = mode; ga.C = C;
    k_gemm<<<dim3(Ncols / 128, 4096 / 128), dim3(256), 0, stream>>>(ga);
  };

  // ---- phase 1 ----
  gemm({{in_h, wx1t_h, 512}, {in_l, wx1t_h, 512}, {in_h, wx1t_l, 512},
        {rh1_h, wh1t_h, 512}, {rh1_l, wh1t_h, 512}, {rh1_h, wh1t_l, 512}}, 2048, b1, 1, Z1);
  k_ew_simple<<<dim3(4096 * 512 / 256), dim3(256), 0, stream>>>(Z1, rnn_c1, nullptr, h1p_h, h1p_l);
  gemm({{h1p_h, wx2t_h, 512}, {h1p_l, wx2t_h, 512}, {h1p_h, wx2t_l, 512},
        {rh2_h, wh2t_h, 512}, {rh2_l, wh2t_h, 512}, {rh2_h, wh2t_l, 512}}, 2048, b2, 1, Z1);
  k_ew_simple<<<dim3(4096 * 512 / 256), dim3(256), 0, stream>>>(Z1, rnn_c2, feat, ft_h, ft_l);
  gemm({{ft_h, cx1ft_h, 512}, {ft_l, cx1ft_h, 512}, {ft_h, cx1ft_l, 512}}, 2048, Cb1, 1, F1);

  // ---- comm scan ----
  for (int t = 0; t < 17; ++t) {
    k_xvar<<<dim3((4096 * 288 + 255) / 256), dim3(256), 0, stream>>>(pres, signals, t, xv_h, xv_l);
    gemm({{xv_h, cx1vt_h, 288}, {xv_l, cx1vt_h, 288}, {xv_h, cx1vt_l, 288},
          {h1_h, ch1t_h, 512}, {h1_l, ch1t_h, 512}, {h1_h, ch1t_l, 512}}, 2048, F1, 2, Z1);
    k_ew_comm1<<<dim3(4096 * 512 / 256), dim3(256), 0, stream>>>(Z1, pres, t, h1, c1, h1_h, h1_l, nh1_h, nh1_l);
    gemm({{nh1_h, cx2t_h, 512}, {nh1_l, cx2t_h, 512}, {nh1_h, cx2t_l, 512},
          {h2_h, ch2t_h, 256}, {h2_l, ch2t_h, 256}, {h2_h, ch2t_l, 256}}, 1024, Cb2, 1, Z2);
    k_ew_comm2<<<dim3(4096 * 256 / 256), dim3(256), 0, stream>>>(Z2, pres, t, h2, c2, h2_h, h2_l);
  }
  k_out<<<dim3(4096 * 1024 / 256), dim3(256), 0, stream>>>(h2, feat, out);
}

// Round 6
// 1869.155 us; speedup vs baseline: 1.6271x; 1.6271x over previous
//
#include <hip/hip_runtime.h>
#include <initializer_list>
#include <cstdint>
#include <cstddef>

// CommCellInnerRNN on MI355X — round 5: plain bf16 GEMM operands (single term,
// was 3-term split-bf16). fp32 accumulate in MFMA. Everything else unchanged.
//   phase1: h1p = LSTM(inputs, rnn_h1, rnn_c1; Wx1,Wh1,b1)
//           feat = LSTM(h1p, rnn_h2, rnn_c2; Wx2,Wh2,b2)
//           F1   = feat @ CWx1[261:773] + Cb1          (features constant over t)
//   loop t=0..16:
//           xvar_t = [gather(signals,pres_t) | onehot(dir) | dist | 0pad] (261->288)
//           z1 = F1 + xvar_t @ CWx1[0:261] + h1 @ CWh1 ; gates -> masked carry
//           z2 = nh1 @ CWx2 + h2 @ CWh2 + Cb2          ; gates -> masked carry
//   out = [h2_final, h2_final, feat]

typedef short short8 __attribute__((ext_vector_type(8)));
typedef float f32x4 __attribute__((ext_vector_type(4)));
typedef unsigned short us;

#define N_AG 4096

// ---------- numeric helpers ----------
__device__ __forceinline__ us f2bf(float x) {
  unsigned int u = __float_as_uint(x);
  unsigned int r = (u + 0x7fffu + ((u >> 16) & 1u)) >> 16;  // RNE
  return (us)r;
}
__device__ __forceinline__ float sigm(float x) { return 1.f / (1.f + __expf(-x)); }
__device__ __forceinline__ float tanh_f(float x) {
  float e = __expf(2.f * x);
  return 1.f - 2.f / (1.f + e);
}

// ---------- GEMM: C[M=4096 x N] = base + sum_p A_p(MxK_p) * B_p^T(NxK_p) ----------
// A,B bf16 row-major (ld=K). 128x128 tile, 4 waves, 16x16x32 MFMA,
// global_load_lds(16B) staging, XOR k-slot swizzle (<=2-way LDS bank alias).
struct Pair { const us* A; const us* B; int K; };
struct GemmArgs { Pair pr[6]; int np; int N; const float* base; int mode; float* C; };

typedef __attribute__((address_space(1))) const unsigned int as1u;
typedef __attribute__((address_space(3))) unsigned int as3u;
__device__ __forceinline__ void gload16(const void* g, void* l) {
  __builtin_amdgcn_global_load_lds((as1u*)g, (as3u*)l, 16, 0, 0);
}

__global__ __launch_bounds__(256) void k_gemm(GemmArgs g) {
  __shared__ __align__(16) us lA[128 * 32];
  __shared__ __align__(16) us lB[128 * 32];
  const int t = threadIdx.x;
  const int w = t >> 6, l = t & 63;
  const int bm = blockIdx.y, bn = blockIdx.x;
  const int wm = w & 1, wn = w >> 1;
  const int fr = l & 15, ks = l >> 4;
  const int srow = t >> 2;                          // staging row (0..63; +64 round 1)
  const int sslot = (t & 3) ^ ((srow >> 1) & 3);    // swizzled source k-slot
  f32x4 acc[4][4] = {};

  for (int p = 0; p < g.np; ++p) {
    const us* A = g.pr[p].A;
    const us* B = g.pr[p].B;
    const int K = g.pr[p].K;
    const us* Ab = A + (size_t)bm * 128 * K;
    const us* Bb = B + (size_t)bn * 128 * K;
    for (int k0 = 0; k0 < K; k0 += 32) {
      __syncthreads();
#pragma unroll
      for (int r = 0; r < 2; ++r) {
        const int row = srow + r * 64;
        gload16(Ab + (size_t)row * K + k0 + sslot * 8, (char*)lA + r * 4096 + w * 1024);
        gload16(Bb + (size_t)row * K + k0 + sslot * 8, (char*)lB + r * 4096 + w * 1024);
      }
      __syncthreads();
      short8 af[4], bfr[4];
#pragma unroll
      for (int mi = 0; mi < 4; ++mi) {
        const int row = wm * 64 + mi * 16 + fr;
        af[mi] = *(const short8*)((const char*)lA + row * 64 + ((ks ^ ((row >> 1) & 3)) * 16));
      }
#pragma unroll
      for (int ni = 0; ni < 4; ++ni) {
        const int row = wn * 64 + ni * 16 + fr;
        bfr[ni] = *(const short8*)((const char*)lB + row * 64 + ((ks ^ ((row >> 1) & 3)) * 16));
      }
#pragma unroll
      for (int mi = 0; mi < 4; ++mi)
#pragma unroll
        for (int ni = 0; ni < 4; ++ni)
          acc[mi][ni] = __builtin_amdgcn_mfma_f32_16x16x32_bf16(af[mi], bfr[ni], acc[mi][ni], 0, 0, 0);
    }
  }
  const int N = g.N;
#pragma unroll
  for (int mi = 0; mi < 4; ++mi) {
#pragma unroll
    for (int ni = 0; ni < 4; ++ni) {
#pragma unroll
      for (int rr = 0; rr < 4; ++rr) {
        const int grow = bm * 128 + wm * 64 + mi * 16 + ks * 4 + rr;
        const int gcol = bn * 128 + wn * 64 + ni * 16 + fr;
        float v = acc[mi][ni][rr];
        if (g.mode == 1) v += g.base[gcol];
        else if (g.mode == 2) v += g.base[(size_t)grow * N + gcol];
        g.C[(size_t)grow * N + gcol] = v;
      }
    }
  }
}

// ---------- weight transpose: src (Krows x Nout) -> bf16 (Nout x Kpad) ----------
__global__ __launch_bounds__(256) void k_transpose(const float* __restrict__ src,
    int Nout, int Kreal, int Kpad, int roff, us* __restrict__ dst) {
  int idx = blockIdx.x * 256 + threadIdx.x;
  if (idx >= Nout * Kpad) return;
  int no = idx % Nout;     // consecutive threads -> coalesced src read
  int k = idx / Nout;
  float v = (k < Kreal) ? src[(size_t)(roff + k) * Nout + no] : 0.f;
  dst[(size_t)no * Kpad + k] = f2bf(v);
}

// ---------- fp32 -> (optional fp32 copy) + bf16 ----------
__global__ __launch_bounds__(256) void k_split(const float* __restrict__ src, int n,
    float* __restrict__ f, us* __restrict__ b) {
  int idx = blockIdx.x * 256 + threadIdx.x;
  if (idx >= n) return;
  float v = src[idx];
  if (f) f[idx] = v;
  if (b) b[idx] = f2bf(v);
}

// ---------- per-step varying input: [gather(256) | onehot(4) | dist(1) | 0pad(27)] ----------
__global__ __launch_bounds__(256) void k_xvar(const int* __restrict__ pi,
    const float* __restrict__ sig, int t, us* __restrict__ xb) {
  int idx = blockIdx.x * 256 + threadIdx.x;
  if (idx >= N_AG * 288) return;
  int n = idx / 288, c = idx - n * 288;
  float v = 0.f;
  if (t < 16) {
    int p = pi[n * 48 + 3 * t];
    if (c < 256) v = (p >= 0) ? sig[(size_t)p * 256 + c] : 0.f;
    else if (c < 260) v = ((c - 256) == pi[n * 48 + 3 * t + 2]) ? 1.f : 0.f;
    else if (c == 260) v = (float)pi[n * 48 + 3 * t + 1];
  } else {
    if (c < 256) v = sig[(size_t)n * 256 + c];  // self row; onehot/dist padded 0
  }
  xb[idx] = f2bf(v);
}

// ---------- LSTM gate kernels ----------
__global__ __launch_bounds__(256) void k_ew_simple(const float* __restrict__ Z,
    const float* __restrict__ cin, float* __restrict__ hf, us* __restrict__ hb) {
  int idx = blockIdx.x * 256 + threadIdx.x;
  if (idx >= N_AG * 512) return;
  int n = idx >> 9, u = idx & 511;
  const float* zr = Z + (size_t)n * 2048;
  float nc = sigm(zr[512 + u]) * cin[idx] + sigm(zr[u]) * tanh_f(zr[1024 + u]);
  float nh = sigm(zr[1536 + u]) * tanh_f(nc);
  if (hf) hf[idx] = nh;
  hb[idx] = f2bf(nh);
}

__global__ __launch_bounds__(256) void k_ew_comm1(const float* __restrict__ Z,
    const int* __restrict__ pi, int t, float* __restrict__ h, float* __restrict__ c,
    us* __restrict__ hb, us* __restrict__ nhb) {
  int idx = blockIdx.x * 256 + threadIdx.x;
  if (idx >= N_AG * 512) return;
  int n = idx >> 9, u = idx & 511;
  const float* zr = Z + (size_t)n * 2048;
  float cold = c[idx];
  float nc = sigm(zr[512 + u]) * cold + sigm(zr[u]) * tanh_f(zr[1024 + u]);
  float nh = sigm(zr[1536 + u]) * tanh_f(nc);
  bool m = (t == 16) ? true : (pi[n * 48 + 3 * t] >= 0);
  float hn = m ? nh : h[idx];
  float cn = m ? nc : cold;
  h[idx] = hn;
  c[idx] = cn;
  hb[idx] = f2bf(hn);    // masked carry (next-step GEMM)
  nhb[idx] = f2bf(nh);   // pre-mask nh1 (layer-2 input)
}

__global__ __launch_bounds__(256) void k_ew_comm2(const float* __restrict__ Z,
    const int* __restrict__ pi, int t, float* __restrict__ h, float* __restrict__ c,
    us* __restrict__ hb) {
  int idx = blockIdx.x * 256 + threadIdx.x;
  if (idx >= N_AG * 256) return;
  int n = idx >> 8, u = idx & 255;
  const float* zr = Z + (size_t)n * 1024;
  float cold = c[idx];
  float nc = sigm(zr[256 + u]) * cold + sigm(zr[u]) * tanh_f(zr[512 + u]);
  float nh = sigm(zr[768 + u]) * tanh_f(nc);
  bool m = (t == 16) ? true : (pi[n * 48 + 3 * t] >= 0);
  float hn = m ? nh : h[idx];
  float cn = m ? nc : cold;
  h[idx] = hn;
  c[idx] = cn;
  hb[idx] = f2bf(hn);
}

__global__ __launch_bounds__(256) void k_out(const float* __restrict__ h2,
    const float* __restrict__ feat, float* __restrict__ out) {
  int idx = blockIdx.x * 256 + threadIdx.x;
  if (idx >= N_AG * 1024) return;
  int n = idx >> 10, cc = idx & 1023;
  out[idx] = (cc < 512) ? h2[(size_t)n * 256 + (cc & 255)] : feat[(size_t)n * 512 + cc - 512];
}

// ---------- host ----------
extern "C" void kernel_launch(void* const* d_in, const int* in_sizes, int n_in,
                              void* d_out, int out_size, void* d_ws, size_t ws_size,
                              hipStream_t stream) {
  const float* inputs  = (const float*)d_in[0];
  const int*   pres    = (const int*)d_in[1];
  const float* rnn_h1  = (const float*)d_in[2];
  const float* rnn_c1  = (const float*)d_in[3];
  const float* rnn_h2  = (const float*)d_in[4];
  const float* rnn_c2  = (const float*)d_in[5];
  const float* comm_h1 = (const float*)d_in[6];
  const float* comm_c1 = (const float*)d_in[7];
  const float* comm_h2 = (const float*)d_in[8];
  const float* comm_c2 = (const float*)d_in[9];
  const float* signals = (const float*)d_in[10];
  const float* Wx1 = (const float*)d_in[11];
  const float* Wh1 = (const float*)d_in[12];
  const float* b1  = (const float*)d_in[13];
  const float* Wx2 = (const float*)d_in[14];
  const float* Wh2 = (const float*)d_in[15];
  const float* b2  = (const float*)d_in[16];
  const float* CWx1 = (const float*)d_in[17];
  const float* CWh1 = (const float*)d_in[18];
  const float* Cb1  = (const float*)d_in[19];
  const float* CWx2 = (const float*)d_in[20];
  const float* CWh2 = (const float*)d_in[21];
  const float* Cb2  = (const float*)d_in[22];
  float* out = (float*)d_out;
  (void)in_sizes; (void)n_in; (void)out_size;

  char* wsb = (char*)d_ws;
  size_t off = 0;
  auto alloc = [&](size_t bytes) -> char* {
    char* p = wsb + off;
    off = (off + bytes + 255) & ~(size_t)255;
    return p;
  };
  // transposed bf16 weights (Nout x Kpad)
  us* wx1t = (us*)alloc(2048 * 512 * 2);
  us* wh1t = (us*)alloc(2048 * 512 * 2);
  us* wx2t = (us*)alloc(2048 * 512 * 2);
  us* wh2t = (us*)alloc(2048 * 512 * 2);
  us* cx1vt = (us*)alloc(2048 * 288 * 2);
  us* cx1ft = (us*)alloc(2048 * 512 * 2);
  us* ch1t = (us*)alloc(2048 * 512 * 2);
  us* cx2t = (us*)alloc(1024 * 512 * 2);
  us* ch2t = (us*)alloc(1024 * 256 * 2);
  // bf16 activations
  us* in_b  = (us*)alloc(4096 * 512 * 2);
  us* rh1_b = (us*)alloc(4096 * 512 * 2);
  us* rh2_b = (us*)alloc(4096 * 512 * 2);
  us* h1p_b = (us*)alloc(4096 * 512 * 2);
  us* ft_b  = (us*)alloc(4096 * 512 * 2);
  us* h1_b  = (us*)alloc(4096 * 512 * 2);
  us* nh1_b = (us*)alloc(4096 * 512 * 2);
  us* h2_b  = (us*)alloc(4096 * 256 * 2);
  us* xv_b  = (us*)alloc(4096 * 288 * 2);
  // fp32 buffers
  float* feat = (float*)alloc(4096 * 512 * 4);
  float* F1 = (float*)alloc((size_t)4096 * 2048 * 4);
  float* Z1 = (float*)alloc((size_t)4096 * 2048 * 4);
  float* Z2 = (float*)alloc((size_t)4096 * 1024 * 4);
  float* h1 = (float*)alloc(4096 * 512 * 4);
  float* c1 = (float*)alloc(4096 * 512 * 4);
  float* h2 = (float*)alloc(4096 * 256 * 4);
  float* c2 = (float*)alloc(4096 * 256 * 4);
  if (off > ws_size) return;  // workspace too small; cannot run safely

  auto tsp = [&](const float* src, int Nout, int Kreal, int Kpad, int roff, us* dst) {
    int tot = Nout * Kpad;
    k_transpose<<<dim3((tot + 255) / 256), dim3(256), 0, stream>>>(src, Nout, Kreal, Kpad, roff, dst);
  };
  tsp(Wx1, 2048, 512, 512, 0, wx1t);
  tsp(Wh1, 2048, 512, 512, 0, wh1t);
  tsp(Wx2, 2048, 512, 512, 0, wx2t);
  tsp(Wh2, 2048, 512, 512, 0, wh2t);
  tsp(CWx1, 2048, 261, 288, 0, cx1vt);      // varying rows 0..260 -> Kpad 288
  tsp(CWx1, 2048, 512, 512, 261, cx1ft);    // feature rows 261..772
  tsp(CWh1, 2048, 512, 512, 0, ch1t);
  tsp(CWx2, 1024, 512, 512, 0, cx2t);
  tsp(CWh2, 1024, 256, 256, 0, ch2t);

  auto spl = [&](const float* src, int n, float* f, us* b) {
    k_split<<<dim3((n + 255) / 256), dim3(256), 0, stream>>>(src, n, f, b);
  };
  spl(inputs, 4096 * 512, nullptr, in_b);
  spl(rnn_h1, 4096 * 512, nullptr, rh1_b);
  spl(rnn_h2, 4096 * 512, nullptr, rh2_b);
  spl(comm_h1, 4096 * 512, h1, h1_b);
  spl(comm_c1, 4096 * 512, c1, nullptr);
  spl(comm_h2, 4096 * 256, h2, h2_b);
  spl(comm_c2, 4096 * 256, c2, nullptr);

  auto gemm = [&](std::initializer_list<Pair> ps, int Ncols, const float* base, int mode, float* C) {
    GemmArgs ga{};
    int i = 0;
    for (auto& p : ps) ga.pr[i++] = p;
    ga.np = i; ga.N = Ncols; ga.base = base; ga.mode = mode; ga.C = C;
    k_gemm<<<dim3(Ncols / 128, 4096 / 128), dim3(256), 0, stream>>>(ga);
  };

  // ---- phase 1 ----
  gemm({{in_b, wx1t, 512}, {rh1_b, wh1t, 512}}, 2048, b1, 1, Z1);
  k_ew_simple<<<dim3(4096 * 512 / 256), dim3(256), 0, stream>>>(Z1, rnn_c1, nullptr, h1p_b);
  gemm({{h1p_b, wx2t, 512}, {rh2_b, wh2t, 512}}, 2048, b2, 1, Z1);
  k_ew_simple<<<dim3(4096 * 512 / 256), dim3(256), 0, stream>>>(Z1, rnn_c2, feat, ft_b);
  gemm({{ft_b, cx1ft, 512}}, 2048, Cb1, 1, F1);

  // ---- comm scan ----
  for (int t = 0; t < 17; ++t) {
    k_xvar<<<dim3((4096 * 288 + 255) / 256), dim3(256), 0, stream>>>(pres, signals, t, xv_b);
    gemm({{xv_b, cx1vt, 288}, {h1_b, ch1t, 512}}, 2048, F1, 2, Z1);
    k_ew_comm1<<<dim3(4096 * 512 / 256), dim3(256), 0, stream>>>(Z1, pres, t, h1, c1, h1_b, nh1_b);
    gemm({{nh1_b, cx2t, 512}, {h2_b, ch2t, 256}}, 1024, Cb2, 1, Z2);
    k_ew_comm2<<<dim3(4096 * 256 / 256), dim3(256), 0, stream>>>(Z2, pres, t, h2, c2, h2_b);
  }
  k_out<<<dim3(4096 * 1024 / 256), dim3(256), 0, stream>>>(h2, feat, out);
}

// Round 8
// 1504.228 us; speedup vs baseline: 2.0219x; 1.2426x over previous
//
#include <hip/hip_runtime.h>
#include <initializer_list>
#include <cstdint>
#include <cstddef>

// CommCellInnerRNN on MI355X — round 6:
//  (1) LSTM gates fused into GEMM epilogue (gate-interleaved weight columns:
//      col = 64*(u>>4) + 16*gate + (u&15) => acc[mi][ni] = gate ni of one unit)
//  (2) BK=64 K-steps (half the barriers), 8-slot XOR LDS swizzle (2-way max)
//  (3) h1_b/h2_b ping-pong (carry is GEMM operand AND epilogue output)
// Z1/Z2 buffers and all separate elementwise gate kernels are gone.

typedef short short8 __attribute__((ext_vector_type(8)));
typedef float f32x4 __attribute__((ext_vector_type(4)));
typedef unsigned short us;

#define N_AG 4096

__device__ __forceinline__ us f2bf(float x) {
  unsigned int u = __float_as_uint(x);
  unsigned int r = (u + 0x7fffu + ((u >> 16) & 1u)) >> 16;  // RNE
  return (us)r;
}
__device__ __forceinline__ float sigm(float x) { return 1.f / (1.f + __expf(-x)); }
__device__ __forceinline__ float tanh_f(float x) {
  float e = __expf(2.f * x);
  return 1.f - 2.f / (1.f + e);
}

struct Pair { const us* A; const us* B; int K; };
struct GemmArgs {
  Pair pr[2]; int np; int N; int nunits;
  const float* bias;    // orig-ordered bias [gate*nunits+u]; used if base2==null
  const float* base2;   // full fp32 base (F1, interleaved cols), else null
  const float* cin;     // c_old  [row*nunits+u]
  float* cout;          // c_new  (null: don't store)
  const float* hold;    // h_old for mask keep (null: hn = nh)
  float* hout;          // h_new fp32 (null: skip)
  us* hb;               // h_new bf16 (always written)
  us* nhb;              // pre-mask nh bf16 (null: skip)
  const int* pres; int tt;  // tt=-1: no mask; tt==16: mask forced true
  float* C; int mode;       // mode 0: plain C=acc+bias (F1); mode 1: LSTM
};

typedef __attribute__((address_space(1))) const unsigned int as1u;
typedef __attribute__((address_space(3))) unsigned int as3u;
__device__ __forceinline__ void gload16(const void* g, void* l) {
  __builtin_amdgcn_global_load_lds((as1u*)g, (as3u*)l, 16, 0, 0);
}

__global__ __launch_bounds__(256) void k_gemm(GemmArgs g) {
  __shared__ __align__(16) us lA[128 * 64];   // 128 rows x 128B
  __shared__ __align__(16) us lB[128 * 64];
  const int t = threadIdx.x;
  const int w = t >> 6, l = t & 63;
  const int bm = blockIdx.y, bn = blockIdx.x;
  const int wm = w & 1, wn = w >> 1;
  const int fr = l & 15, ks = l >> 4;
  f32x4 acc[4][4] = {};

  for (int p = 0; p < g.np; ++p) {
    const us* A = g.pr[p].A;
    const us* B = g.pr[p].B;
    const int K = g.pr[p].K;
    const us* Ab = A + (size_t)bm * 128 * K;
    const us* Bb = B + (size_t)bn * 128 * K;
    for (int k0 = 0; k0 < K; k0 += 64) {
      __syncthreads();
#pragma unroll
      for (int r0 = 0; r0 < 4; ++r0) {
        const int srow = r0 * 32 + (t >> 3);
        const int sslot = (t & 7) ^ (srow & 7);   // inverse-swizzled source slot
        gload16(Ab + (size_t)srow * K + k0 + sslot * 8, (char*)lA + r0 * 4096 + w * 1024);
        gload16(Bb + (size_t)srow * K + k0 + sslot * 8, (char*)lB + r0 * 4096 + w * 1024);
      }
      __syncthreads();
#pragma unroll
      for (int kh = 0; kh < 2; ++kh) {
        short8 af[4], bf[4];
#pragma unroll
        for (int mi = 0; mi < 4; ++mi) {
          const int row = wm * 64 + mi * 16 + fr;
          const int s = kh * 4 + ks;
          af[mi] = *(const short8*)((const char*)lA + row * 128 + ((s ^ (row & 7)) << 4));
        }
#pragma unroll
        for (int ni = 0; ni < 4; ++ni) {
          const int row = wn * 64 + ni * 16 + fr;
          const int s = kh * 4 + ks;
          bf[ni] = *(const short8*)((const char*)lB + row * 128 + ((s ^ (row & 7)) << 4));
        }
#pragma unroll
        for (int mi = 0; mi < 4; ++mi)
#pragma unroll
          for (int ni = 0; ni < 4; ++ni)
            acc[mi][ni] = __builtin_amdgcn_mfma_f32_16x16x32_bf16(af[mi], bf[ni], acc[mi][ni], 0, 0, 0);
      }
    }
  }

  const int N = g.N, nu = g.nunits;
  const int u = (bn * 2 + wn) * 16 + fr;          // unit owned by this thread
  if (g.mode == 0) {
#pragma unroll
    for (int mi = 0; mi < 4; ++mi)
#pragma unroll
      for (int ni = 0; ni < 4; ++ni)
#pragma unroll
        for (int rr = 0; rr < 4; ++rr) {
          const int grow = bm * 128 + wm * 64 + mi * 16 + ks * 4 + rr;
          const int col = bn * 128 + wn * 64 + ni * 16 + fr;
          g.C[(size_t)grow * N + col] = acc[mi][ni][rr] + g.bias[ni * nu + u];
        }
    return;
  }
  // LSTM epilogue: acc[mi][0..3] = gates i,f,g,o of unit u
  float bi = 0.f, bfg = 0.f, bg = 0.f, bo = 0.f;
  if (!g.base2) { bi = g.bias[u]; bfg = g.bias[nu + u]; bg = g.bias[2 * nu + u]; bo = g.bias[3 * nu + u]; }
#pragma unroll
  for (int mi = 0; mi < 4; ++mi) {
#pragma unroll
    for (int rr = 0; rr < 4; ++rr) {
      const int grow = bm * 128 + wm * 64 + mi * 16 + ks * 4 + rr;
      float zi = acc[mi][0][rr], zf = acc[mi][1][rr], zg = acc[mi][2][rr], zo = acc[mi][3][rr];
      if (g.base2) {
        const float* fb = g.base2 + (size_t)grow * N + bn * 128 + wn * 64 + fr;
        zi += fb[0]; zf += fb[16]; zg += fb[32]; zo += fb[48];
      } else {
        zi += bi; zf += bfg; zg += bg; zo += bo;
      }
      const size_t off = (size_t)grow * nu + u;
      const float cold = g.cin[off];
      const float nc = sigm(zf) * cold + sigm(zi) * tanh_f(zg);
      const float nh = sigm(zo) * tanh_f(nc);
      bool m = true;
      if (g.tt >= 0 && g.tt < 16) m = (g.pres[grow * 48 + 3 * g.tt] >= 0);
      const float cn = m ? nc : cold;
      float hn = nh;
      if (g.hold) hn = m ? nh : g.hold[off];
      if (g.cout) g.cout[off] = cn;
      if (g.hout) g.hout[off] = hn;
      g.hb[off] = f2bf(hn);
      if (g.nhb) g.nhb[off] = f2bf(nh);
    }
  }
}

// weight transpose + gate-interleave: src (Krows x Nout) -> dst (Nout x Kpad)
// new column col <=> (gate=(col>>4)&3, u=((col>>6)<<4)|(col&15)); orig = gate*nunits+u
__global__ __launch_bounds__(256) void k_transpose(const float* __restrict__ src,
    int Nout, int nunits, int Kreal, int Kpad, int roff, us* __restrict__ dst) {
  int idx = blockIdx.x * 256 + threadIdx.x;
  if (idx >= Nout * Kpad) return;
  int col = idx % Nout;
  int k = idx / Nout;
  int gate = (col >> 4) & 3;
  int u = ((col >> 6) << 4) | (col & 15);
  float v = (k < Kreal) ? src[(size_t)(roff + k) * Nout + gate * nunits + u] : 0.f;
  dst[(size_t)col * Kpad + k] = f2bf(v);
}

__global__ __launch_bounds__(256) void k_split(const float* __restrict__ src, int n,
    float* __restrict__ f, us* __restrict__ b) {
  int idx = blockIdx.x * 256 + threadIdx.x;
  if (idx >= n) return;
  float v = src[idx];
  if (f) f[idx] = v;
  if (b) b[idx] = f2bf(v);
}

// per-step varying input: [gather(256) | onehot(4) | dist(1) | 0pad(59)] -> 320 cols
__global__ __launch_bounds__(256) void k_xvar(const int* __restrict__ pi,
    const float* __restrict__ sig, int t, us* __restrict__ xb) {
  int idx = blockIdx.x * 256 + threadIdx.x;
  if (idx >= N_AG * 320) return;
  int n = idx / 320, c = idx - n * 320;
  float v = 0.f;
  if (t < 16) {
    int p = pi[n * 48 + 3 * t];
    if (c < 256) v = (p >= 0) ? sig[(size_t)p * 256 + c] : 0.f;
    else if (c < 260) v = ((c - 256) == pi[n * 48 + 3 * t + 2]) ? 1.f : 0.f;
    else if (c == 260) v = (float)pi[n * 48 + 3 * t + 1];
  } else {
    if (c < 256) v = sig[(size_t)n * 256 + c];  // self row
  }
  xb[idx] = f2bf(v);
}

__global__ __launch_bounds__(256) void k_out(const float* __restrict__ h2,
    const float* __restrict__ feat, float* __restrict__ out) {
  int idx = blockIdx.x * 256 + threadIdx.x;
  if (idx >= N_AG * 1024) return;
  int n = idx >> 10, cc = idx & 1023;
  out[idx] = (cc < 512) ? h2[(size_t)n * 256 + (cc & 255)] : feat[(size_t)n * 512 + cc - 512];
}

// ---------- host ----------
extern "C" void kernel_launch(void* const* d_in, const int* in_sizes, int n_in,
                              void* d_out, int out_size, void* d_ws, size_t ws_size,
                              hipStream_t stream) {
  const float* inputs  = (const float*)d_in[0];
  const int*   pres    = (const int*)d_in[1];
  const float* rnn_h1  = (const float*)d_in[2];
  const float* rnn_c1  = (const float*)d_in[3];
  const float* rnn_h2  = (const float*)d_in[4];
  const float* rnn_c2  = (const float*)d_in[5];
  const float* comm_h1 = (const float*)d_in[6];
  const float* comm_c1 = (const float*)d_in[7];
  const float* comm_h2 = (const float*)d_in[8];
  const float* comm_c2 = (const float*)d_in[9];
  const float* signals = (const float*)d_in[10];
  const float* Wx1 = (const float*)d_in[11];
  const float* Wh1 = (const float*)d_in[12];
  const float* b1  = (const float*)d_in[13];
  const float* Wx2 = (const float*)d_in[14];
  const float* Wh2 = (const float*)d_in[15];
  const float* b2  = (const float*)d_in[16];
  const float* CWx1 = (const float*)d_in[17];
  const float* CWh1 = (const float*)d_in[18];
  const float* Cb1  = (const float*)d_in[19];
  const float* CWx2 = (const float*)d_in[20];
  const float* CWh2 = (const float*)d_in[21];
  const float* Cb2  = (const float*)d_in[22];
  float* out = (float*)d_out;
  (void)in_sizes; (void)n_in; (void)out_size;

  char* wsb = (char*)d_ws;
  size_t off = 0;
  auto alloc = [&](size_t bytes) -> char* {
    char* p = wsb + off;
    off = (off + bytes + 255) & ~(size_t)255;
    return p;
  };
  // interleaved transposed bf16 weights (Nout x Kpad)
  us* wx1t  = (us*)alloc(2048 * 512 * 2);
  us* wh1t  = (us*)alloc(2048 * 512 * 2);
  us* wx2t  = (us*)alloc(2048 * 512 * 2);
  us* wh2t  = (us*)alloc(2048 * 512 * 2);
  us* cx1vt = (us*)alloc(2048 * 320 * 2);
  us* cx1ft = (us*)alloc(2048 * 512 * 2);
  us* ch1t  = (us*)alloc(2048 * 512 * 2);
  us* cx2t  = (us*)alloc(1024 * 512 * 2);
  us* ch2t  = (us*)alloc(1024 * 256 * 2);
  // bf16 activations
  us* in_b   = (us*)alloc(4096 * 512 * 2);
  us* rh1_b  = (us*)alloc(4096 * 512 * 2);
  us* rh2_b  = (us*)alloc(4096 * 512 * 2);
  us* h1p_b  = (us*)alloc(4096 * 512 * 2);
  us* ft_b   = (us*)alloc(4096 * 512 * 2);
  us* h1b0   = (us*)alloc(4096 * 512 * 2);
  us* h1b1   = (us*)alloc(4096 * 512 * 2);
  us* nh1_b  = (us*)alloc(4096 * 512 * 2);
  us* h2b0   = (us*)alloc(4096 * 256 * 2);
  us* h2b1   = (us*)alloc(4096 * 256 * 2);
  us* xv_b   = (us*)alloc(4096 * 320 * 2);
  // fp32 buffers
  float* feat = (float*)alloc(4096 * 512 * 4);
  float* F1   = (float*)alloc((size_t)4096 * 2048 * 4);
  float* h1 = (float*)alloc(4096 * 512 * 4);
  float* c1 = (float*)alloc(4096 * 512 * 4);
  float* h2 = (float*)alloc(4096 * 256 * 4);
  float* c2 = (float*)alloc(4096 * 256 * 4);
  if (off > ws_size) return;

  auto tsp = [&](const float* src, int Nout, int Kreal, int Kpad, int roff, us* dst) {
    int tot = Nout * Kpad;
    k_transpose<<<dim3((tot + 255) / 256), dim3(256), 0, stream>>>(src, Nout, Nout / 4, Kreal, Kpad, roff, dst);
  };
  tsp(Wx1, 2048, 512, 512, 0, wx1t);
  tsp(Wh1, 2048, 512, 512, 0, wh1t);
  tsp(Wx2, 2048, 512, 512, 0, wx2t);
  tsp(Wh2, 2048, 512, 512, 0, wh2t);
  tsp(CWx1, 2048, 261, 320, 0, cx1vt);     // varying rows 0..260 -> Kpad 320
  tsp(CWx1, 2048, 512, 512, 261, cx1ft);   // feature rows 261..772
  tsp(CWh1, 2048, 512, 512, 0, ch1t);
  tsp(CWx2, 1024, 512, 512, 0, cx2t);
  tsp(CWh2, 1024, 256, 256, 0, ch2t);

  auto spl = [&](const float* src, int n, float* f, us* b) {
    k_split<<<dim3((n + 255) / 256), dim3(256), 0, stream>>>(src, n, f, b);
  };
  spl(inputs, 4096 * 512, nullptr, in_b);
  spl(rnn_h1, 4096 * 512, nullptr, rh1_b);
  spl(rnn_h2, 4096 * 512, nullptr, rh2_b);
  spl(comm_h1, 4096 * 512, h1, h1b0);
  spl(comm_c1, 4096 * 512, c1, nullptr);
  spl(comm_h2, 4096 * 256, h2, h2b0);
  spl(comm_c2, 4096 * 256, c2, nullptr);

  auto launch = [&](GemmArgs& ga) {
    k_gemm<<<dim3(ga.N / 128, 4096 / 128), dim3(256), 0, stream>>>(ga);
  };
  auto lstm = [&](std::initializer_list<Pair> ps, int Ncols, const float* bias, const float* base2,
                  const float* cin, float* cout, const float* hold, float* hout,
                  us* hb, us* nhb, const int* pm, int tt) {
    GemmArgs ga{};
    int i = 0;
    for (auto& p : ps) ga.pr[i++] = p;
    ga.np = i; ga.N = Ncols; ga.nunits = Ncols / 4;
    ga.bias = bias; ga.base2 = base2; ga.cin = cin; ga.cout = cout;
    ga.hold = hold; ga.hout = hout; ga.hb = hb; ga.nhb = nhb;
    ga.pres = pm; ga.tt = tt; ga.C = nullptr; ga.mode = 1;
    launch(ga);
  };
  auto plain = [&](std::initializer_list<Pair> ps, int Ncols, const float* bias, float* C) {
    GemmArgs ga{};
    int i = 0;
    for (auto& p : ps) ga.pr[i++] = p;
    ga.np = i; ga.N = Ncols; ga.nunits = Ncols / 4;
    ga.bias = bias; ga.C = C; ga.mode = 0; ga.tt = -1;
    launch(ga);
  };

  // ---- phase 1 ----
  lstm({{in_b, wx1t, 512}, {rh1_b, wh1t, 512}}, 2048, b1, nullptr,
       rnn_c1, nullptr, nullptr, nullptr, h1p_b, nullptr, nullptr, -1);
  lstm({{h1p_b, wx2t, 512}, {rh2_b, wh2t, 512}}, 2048, b2, nullptr,
       rnn_c2, nullptr, nullptr, feat, ft_b, nullptr, nullptr, -1);
  plain({{ft_b, cx1ft, 512}}, 2048, Cb1, F1);

  // ---- comm scan (h*_b ping-pong: step t reads [t&1], writes [(t+1)&1]) ----
  us* h1bp[2] = {h1b0, h1b1};
  us* h2bp[2] = {h2b0, h2b1};
  for (int t = 0; t < 17; ++t) {
    const int rd = t & 1, wr = rd ^ 1;
    k_xvar<<<dim3((4096 * 320 + 255) / 256), dim3(256), 0, stream>>>(pres, signals, t, xv_b);
    lstm({{xv_b, cx1vt, 320}, {h1bp[rd], ch1t, 512}}, 2048, nullptr, F1,
         c1, c1, h1, h1, h1bp[wr], nh1_b, pres, t);
    lstm({{nh1_b, cx2t, 512}, {h2bp[rd], ch2t, 256}}, 1024, Cb2, nullptr,
         c2, c2, h2, h2, h2bp[wr], nullptr, pres, t);
  }
  k_out<<<dim3(4096 * 1024 / 256), dim3(256), 0, stream>>>(h2, feat, out);
}